// Round 15
// baseline (1473.594 us; speedup 1.0000x reference)
//
#include <hip/hip_runtime.h>
#include <hip/hip_bf16.h>

// GGCN: g1=relu(A@(x@W1)+b1); g2=relu(A@(g1@W2)+b2); out=relu(g2@Wd1+bd1)@Wd2+bd2
// N=16384, F=32, H=64, A dense f32 (1.07 GB, read 2x -> HBM floor ~341us).
// R15 = R12 (best, 426us) with sH DELETED: B-frags load directly from
// L2-resident Ht into a DOUBLE register set, prefetched ONE TILE AHEAD
// (R11 issued them at compute time -> serialized; that was its flaw).
// LDS 128->64 KB -> 2 blocks/CU = 8 waves/CU (2x R12): covers the bursty
// load-drain gaps of the barrier-free pipeline. A path byte-identical to R12.

typedef __bf16 bf16x8 __attribute__((ext_vector_type(8)));
typedef float  f32x16 __attribute__((ext_vector_type(16)));
typedef float  f32x4v __attribute__((ext_vector_type(4)));
typedef int    i32x4  __attribute__((ext_vector_type(4)));

#define NNODE 16384
#define KDIM  16384
#define HCOL  64

__device__ inline i32x4 pack8(f32x4v a, f32x4v b){
  bf16x8 t;
  t[0]=(__bf16)a[0]; t[1]=(__bf16)a[1]; t[2]=(__bf16)a[2]; t[3]=(__bf16)a[3];
  t[4]=(__bf16)b[0]; t[5]=(__bf16)b[1]; t[6]=(__bf16)b[2]; t[7]=(__bf16)b[3];
  return __builtin_bit_cast(i32x4, t);
}
#define BC(x) __builtin_bit_cast(bf16x8, x)

// ---------------- big kernel: G = relu(A @ Ht^T + bias) ----------------
// block = 256 thr (4 waves). BM=64 rows. wave kw owns K-quarter kw (wave-private
// LDS dbuf for A only, no main-loop barriers). XOR swizzle chunks: c ^ (row&7).
__global__ __launch_bounds__(256, 2) void gcn_layer_kernel(
    const float* __restrict__ A,      // [16384][16384] f32
    const __bf16* __restrict__ Ht,    // [64][16384] bf16 (transposed H)
    const float* __restrict__ bias,   // [64]
    float* __restrict__ G)            // [16384][64] f32
{
  __shared__ i32x4 sA[4*2*512];   // (kw,buf) x 64 rows x 8 chunks = 64 KB

  const int tid  = threadIdx.x;
  const int lane = tid & 63;
  const int kw   = tid >> 6;          // K-quarter 0..3
  const int row0 = blockIdx.x * 64;

  const int rA0  = lane >> 3;         // 0..7 staging row-in-group
  const int ccA  = lane & 7;          // staging logical 16B chunk (of 8 per 64k)
  const int swzA = ccA ^ rA0;         // row&7 == rA0 for all staged rows
  const int r    = lane & 31;
  const int hsub = lane >> 5;         // 0/1 k-subgroup within 16-k window
  const int xs   = r & 7;

  const size_t k0 = (size_t)kw * 4096;

  f32x4v ra[16];
  i32x4  b0a[4], b1a[4], b0b[4], b1b[4];   // B-frag double set (tile parity)

  const float*  pA0 = A  + (size_t)(row0 + rA0) * KDIM + k0 + (size_t)ccA*8;
  const __bf16* pB0 = Ht + (size_t)r        * KDIM + k0 + (size_t)hsub*8;
  const __bf16* pB1 = pB0 + (size_t)32 * KDIM;

  auto loadA = [&](int t){
    const float* pA = pA0 + (size_t)t*64;
    #pragma unroll
    for (int pi=0; pi<8; ++pi){                    // rows rA0 + pi*8 (64 rows)
      const float* p = pA + (size_t)pi*8*KDIM;
      ra[2*pi]   = *(const f32x4v*)p;              // plain loads [R12-proven]
      ra[2*pi+1] = *(const f32x4v*)(p+4);
    }
  };
  auto loadB = [&](i32x4 (&b0)[4], i32x4 (&b1)[4], int t){
    const __bf16* q0 = pB0 + (size_t)t*64;         // L2-resident, 16B/lane
    const __bf16* q1 = pB1 + (size_t)t*64;
    #pragma unroll
    for (int kk=0; kk<4; ++kk){
      b0[kk] = *(const i32x4*)(q0 + kk*16);
      b1[kk] = *(const i32x4*)(q1 + kk*16);
    }
  };
  auto writeA = [&](int buf){
    i32x4* dA = &sA[(kw*2+buf)*512];
    #pragma unroll
    for (int pi=0; pi<8; ++pi)
      dA[(rA0 + pi*8)*8 + swzA] = pack8(ra[2*pi], ra[2*pi+1]);
  };

  f32x16 acc00 = {}, acc01 = {}, acc10 = {}, acc11 = {};

  auto compute = [&](int buf, i32x4 (&b0)[4], i32x4 (&b1)[4]){
    const i32x4* bA = &sA[(kw*2+buf)*512];
    #pragma unroll
    for (int kk=0; kk<4; ++kk){
      int c = (kk*2 + hsub) ^ xs;                  // (r+32)&7 == r&7 -> same c
      bf16x8 a0 = BC(bA[r*8 + c]);
      bf16x8 a1 = BC(bA[(r+32)*8 + c]);
      acc00 = __builtin_amdgcn_mfma_f32_32x32x16_bf16(a0, BC(b0[kk]), acc00, 0,0,0);
      acc01 = __builtin_amdgcn_mfma_f32_32x32x16_bf16(a0, BC(b1[kk]), acc01, 0,0,0);
      acc10 = __builtin_amdgcn_mfma_f32_32x32x16_bf16(a1, BC(b0[kk]), acc10, 0,0,0);
      acc11 = __builtin_amdgcn_mfma_f32_32x32x16_bf16(a1, BC(b1[kk]), acc11, 0,0,0);
    }
  };

  // barrier-free per-wave pipeline over 64 tiles (k-quarter, 64 k each).
  // B set a = even tiles, set b = odd tiles; always loaded 1 tile ahead.
  loadA(0); loadB(b0a, b1a, 0);
  writeA(0);
  loadA(1); loadB(b0b, b1b, 1);
  #pragma unroll 1
  for (int t=0; t<62; t+=2){
    compute(0, b0a, b1a);              // tile t (even, buf0)
    loadB(b0a, b1a, t+2);              // refill just-consumed set, 1 tile ahead
    writeA(1);                         // tile t+1 -> buf1 (ra loaded last iter)
    loadA(t+2);
    compute(1, b0b, b1b);              // tile t+1 (odd, buf1)
    loadB(b0b, b1b, t+3);
    writeA(0);                         // tile t+2 -> buf0
    loadA(t+3);
  }
  compute(0, b0a, b1a);                // tile 62
  writeA(1);                           // tile 63
  compute(1, b0b, b1b);                // tile 63

  __syncthreads();             // red aliases kw0..2's sA regions

  // split-K=4 reduce: waves 1..3 dump partials, wave 0 combines (R12-identical)
  float* red = (float*)sA;     // 3 x 64x64 f32 = 48 KB (fits in 64 KB sA)
  if (kw > 0){
    float* rd = red + (size_t)(kw-1)*4096;
    #pragma unroll
    for (int j=0; j<16; ++j){
      int rr = (j&3) + 8*(j>>2) + 4*hsub;          // C/D layout [verified R1..R14]
      rd[(rr   )*64 + r]      = acc00[j];
      rd[(rr   )*64 + 32 + r] = acc01[j];
      rd[(rr+32)*64 + r]      = acc10[j];
      rd[(rr+32)*64 + 32 + r] = acc11[j];
    }
  }
  __syncthreads();
  if (kw == 0){
    #pragma unroll
    for (int j=0; j<16; ++j){
      int rr = (j&3) + 8*(j>>2) + 4*hsub;
      float v00 = acc00[j] + red[(rr   )*64+r]    + red[4096+(rr   )*64+r]    + red[8192+(rr   )*64+r]    + bias[r];
      float v01 = acc01[j] + red[(rr   )*64+32+r] + red[4096+(rr   )*64+32+r] + red[8192+(rr   )*64+32+r] + bias[32+r];
      float v10 = acc10[j] + red[(rr+32)*64+r]    + red[4096+(rr+32)*64+r]    + red[8192+(rr+32)*64+r]    + bias[r];
      float v11 = acc11[j] + red[(rr+32)*64+32+r] + red[4096+(rr+32)*64+32+r] + red[8192+(rr+32)*64+32+r] + bias[32+r];
      G[(size_t)(row0 + rr     )*HCOL + r]      = fmaxf(v00, 0.f);
      G[(size_t)(row0 + rr     )*HCOL + 32 + r] = fmaxf(v01, 0.f);
      G[(size_t)(row0 + rr + 32)*HCOL + r]      = fmaxf(v10, 0.f);
      G[(size_t)(row0 + rr + 32)*HCOL + 32 + r] = fmaxf(v11, 0.f);
    }
  }
}

// ---------------- projection: out[h][n] = sum_f in[n][f]*W[f][h], bf16 out ----------------
template<int F>
__global__ __launch_bounds__(128) void proj_T_kernel(
    const float* __restrict__ in,   // [N][F]
    const float* __restrict__ W,    // [F][64]
    __bf16* __restrict__ out)       // [64][N]
{
  constexpr int FP = F + 4;
  __shared__ float sWt[64*FP];
  __shared__ short sOut[64*136];

  int tid = threadIdx.x;
  for (int e = tid; e < 64*F; e += 128){
    int h = e / F, j = e - h*F;
    sWt[h*FP + j] = W[j*64 + h];
  }
  __syncthreads();

  const size_t n = (size_t)blockIdx.x*128 + tid;
  float rowv[F];
  #pragma unroll
  for (int j=0; j<F; j+=4){
    f32x4v v = *(const f32x4v*)(in + n*F + j);
    rowv[j]=v[0]; rowv[j+1]=v[1]; rowv[j+2]=v[2]; rowv[j+3]=v[3];
  }
  #pragma unroll
  for (int h=0; h<64; ++h){
    float s = 0.f;
    #pragma unroll
    for (int j=0; j<F; j+=4){
      f32x4v w = *(const f32x4v*)&sWt[h*FP + j];
      s += rowv[j]*w[0] + rowv[j+1]*w[1] + rowv[j+2]*w[2] + rowv[j+3]*w[3];
    }
    sOut[h*136 + tid] = __builtin_bit_cast(short, (__bf16)s);
  }
  __syncthreads();

  const size_t n0 = (size_t)blockIdx.x*128;
  #pragma unroll
  for (int pi=0; pi<8; ++pi){
    int p = pi*128 + tid;
    int h = p >> 4, cc = p & 15;
    i32x4 v = *(const i32x4*)&sOut[h*136 + cc*8];
    *(i32x4*)(out + (size_t)h*NNODE + n0 + cc*8) = v;
  }
}

// ---------------- tail MLP: out[n] = relu(g2[n]@Wd1+bd1)@Wd2 + bd2 ----------------
__global__ __launch_bounds__(256) void tail_kernel(
    const float* __restrict__ g2,
    const float* __restrict__ Wd1,
    const float* __restrict__ bd1,
    const float* __restrict__ Wd2,
    const float* __restrict__ bd2,
    float* __restrict__ outp)
{
  __shared__ float sW[64*32];
  __shared__ float sb1[32], sw2[32];
  int tid = threadIdx.x;
  for (int e=tid; e<2048; e+=256) sW[e] = Wd1[e];
  if (tid < 32){ sb1[tid] = bd1[tid]; sw2[tid] = Wd2[tid]; }
  __syncthreads();

  size_t n = (size_t)blockIdx.x*256 + tid;
  float rv[64];
  #pragma unroll
  for (int j=0;j<64;j+=4){
    f32x4v v = *(const f32x4v*)(g2 + n*64 + j);
    rv[j]=v[0]; rv[j+1]=v[1]; rv[j+2]=v[2]; rv[j+3]=v[3];
  }
  float o = 0.f;
  #pragma unroll
  for (int c=0;c<32;++c){
    float s = sb1[c];
    #pragma unroll
    for (int j=0;j<64;++j) s += rv[j]*sW[j*32 + c];
    o += fmaxf(s, 0.f) * sw2[c];
  }
  outp[n] = o + bd2[0];
}

extern "C" void kernel_launch(void* const* d_in, const int* in_sizes, int n_in,
                              void* d_out, int out_size, void* d_ws, size_t ws_size,
                              hipStream_t stream)
{
  const float* x   = (const float*)d_in[0];
  const float* a   = (const float*)d_in[1];
  const float* W1  = (const float*)d_in[2];
  const float* b1  = (const float*)d_in[3];
  const float* W2  = (const float*)d_in[4];
  const float* b2  = (const float*)d_in[5];
  const float* Wd1 = (const float*)d_in[6];
  const float* bd1 = (const float*)d_in[7];
  const float* Wd2 = (const float*)d_in[8];
  const float* bd2 = (const float*)d_in[9];
  float* outp = (float*)d_out;

  char* ws = (char*)d_ws;                       // needs 12 MB
  __bf16* Ht1 = (__bf16*)(ws);                  // [64][16384] bf16, 2 MB
  __bf16* Ht2 = (__bf16*)(ws + (2u<<20));       // 2 MB
  float*  g1  = (float*)(ws + (4u<<20));        // [16384][64] f32, 4 MB
  float*  g2  = (float*)(ws + (8u<<20));        // 4 MB

  proj_T_kernel<32><<<128, 128, 0, stream>>>(x,  W1, Ht1);
  gcn_layer_kernel <<<256, 256, 0, stream>>>(a, Ht1, b1, g1);
  proj_T_kernel<64><<<128, 128, 0, stream>>>(g1, W2, Ht2);
  gcn_layer_kernel <<<256, 256, 0, stream>>>(a, Ht2, b2, g2);
  tail_kernel      <<<64, 256, 0, stream>>>(g2, Wd1, bd1, Wd2, bd2, outp);
}

// Round 16
// 454.880 us; speedup vs baseline: 3.2395x; 3.2395x over previous
//
#include <hip/hip_runtime.h>
#include <hip/hip_bf16.h>

// GGCN: g1=relu(A@(x@W1)+b1); g2=relu(A@(g1@W2)+b2); out=relu(g2@Wd1+bd1)@Wd2+bd2
// N=16384, F=32, H=64, A dense f32 (1.07 GB, read 2x -> HBM floor ~341us).
// R16 = R15 with ONE fix: __launch_bounds__(256) instead of (256,2).
// R15's counters showed WRITE_SIZE 857MB + VGPR=128 -> the (256,2) bound made
// the allocator spill ~60 regs of staging state to scratch every tile. With
// the default bound the kernel takes ~200 VGPR (no spill) and still gets
// 2 waves/SIMD (512/200), keeping the intended 8 waves/CU from 64KB LDS.
// Structure: sH deleted; B-frags direct from L2-resident Ht in a DOUBLE
// register set prefetched one tile ahead; A path byte-identical to R12.

typedef __bf16 bf16x8 __attribute__((ext_vector_type(8)));
typedef float  f32x16 __attribute__((ext_vector_type(16)));
typedef float  f32x4v __attribute__((ext_vector_type(4)));
typedef int    i32x4  __attribute__((ext_vector_type(4)));

#define NNODE 16384
#define KDIM  16384
#define HCOL  64

__device__ inline i32x4 pack8(f32x4v a, f32x4v b){
  bf16x8 t;
  t[0]=(__bf16)a[0]; t[1]=(__bf16)a[1]; t[2]=(__bf16)a[2]; t[3]=(__bf16)a[3];
  t[4]=(__bf16)b[0]; t[5]=(__bf16)b[1]; t[6]=(__bf16)b[2]; t[7]=(__bf16)b[3];
  return __builtin_bit_cast(i32x4, t);
}
#define BC(x) __builtin_bit_cast(bf16x8, x)

// ---------------- big kernel: G = relu(A @ Ht^T + bias) ----------------
// block = 256 thr (4 waves). BM=64 rows. wave kw owns K-quarter kw (wave-private
// LDS dbuf for A only, no main-loop barriers). XOR swizzle chunks: c ^ (row&7).
__global__ __launch_bounds__(256) void gcn_layer_kernel(
    const float* __restrict__ A,      // [16384][16384] f32
    const __bf16* __restrict__ Ht,    // [64][16384] bf16 (transposed H)
    const float* __restrict__ bias,   // [64]
    float* __restrict__ G)            // [16384][64] f32
{
  __shared__ i32x4 sA[4*2*512];   // (kw,buf) x 64 rows x 8 chunks = 64 KB

  const int tid  = threadIdx.x;
  const int lane = tid & 63;
  const int kw   = tid >> 6;          // K-quarter 0..3
  const int row0 = blockIdx.x * 64;

  const int rA0  = lane >> 3;         // 0..7 staging row-in-group
  const int ccA  = lane & 7;          // staging logical 16B chunk (of 8 per 64k)
  const int swzA = ccA ^ rA0;         // row&7 == rA0 for all staged rows
  const int r    = lane & 31;
  const int hsub = lane >> 5;         // 0/1 k-subgroup within 16-k window
  const int xs   = r & 7;

  const size_t k0 = (size_t)kw * 4096;

  f32x4v ra[16];
  i32x4  b0a[4], b1a[4], b0b[4], b1b[4];   // B-frag double set (tile parity)

  const float*  pA0 = A  + (size_t)(row0 + rA0) * KDIM + k0 + (size_t)ccA*8;
  const __bf16* pB0 = Ht + (size_t)r        * KDIM + k0 + (size_t)hsub*8;
  const __bf16* pB1 = pB0 + (size_t)32 * KDIM;

  auto loadA = [&](int t){
    const float* pA = pA0 + (size_t)t*64;
    #pragma unroll
    for (int pi=0; pi<8; ++pi){                    // rows rA0 + pi*8 (64 rows)
      const float* p = pA + (size_t)pi*8*KDIM;
      ra[2*pi]   = *(const f32x4v*)p;              // plain loads [R12-proven]
      ra[2*pi+1] = *(const f32x4v*)(p+4);
    }
  };
  auto loadB = [&](i32x4 (&b0)[4], i32x4 (&b1)[4], int t){
    const __bf16* q0 = pB0 + (size_t)t*64;         // L2-resident, 16B/lane
    const __bf16* q1 = pB1 + (size_t)t*64;
    #pragma unroll
    for (int kk=0; kk<4; ++kk){
      b0[kk] = *(const i32x4*)(q0 + kk*16);
      b1[kk] = *(const i32x4*)(q1 + kk*16);
    }
  };
  auto writeA = [&](int buf){
    i32x4* dA = &sA[(kw*2+buf)*512];
    #pragma unroll
    for (int pi=0; pi<8; ++pi)
      dA[(rA0 + pi*8)*8 + swzA] = pack8(ra[2*pi], ra[2*pi+1]);
  };

  f32x16 acc00 = {}, acc01 = {}, acc10 = {}, acc11 = {};

  auto compute = [&](int buf, i32x4 (&b0)[4], i32x4 (&b1)[4]){
    const i32x4* bA = &sA[(kw*2+buf)*512];
    #pragma unroll
    for (int kk=0; kk<4; ++kk){
      int c = (kk*2 + hsub) ^ xs;                  // (r+32)&7 == r&7 -> same c
      bf16x8 a0 = BC(bA[r*8 + c]);
      bf16x8 a1 = BC(bA[(r+32)*8 + c]);
      acc00 = __builtin_amdgcn_mfma_f32_32x32x16_bf16(a0, BC(b0[kk]), acc00, 0,0,0);
      acc01 = __builtin_amdgcn_mfma_f32_32x32x16_bf16(a0, BC(b1[kk]), acc01, 0,0,0);
      acc10 = __builtin_amdgcn_mfma_f32_32x32x16_bf16(a1, BC(b0[kk]), acc10, 0,0,0);
      acc11 = __builtin_amdgcn_mfma_f32_32x32x16_bf16(a1, BC(b1[kk]), acc11, 0,0,0);
    }
  };

  // barrier-free per-wave pipeline over 64 tiles (k-quarter, 64 k each).
  // B set a = even tiles, set b = odd tiles; always loaded 1 tile ahead.
  loadA(0); loadB(b0a, b1a, 0);
  writeA(0);
  loadA(1); loadB(b0b, b1b, 1);
  #pragma unroll 1
  for (int t=0; t<62; t+=2){
    compute(0, b0a, b1a);              // tile t (even, buf0)
    loadB(b0a, b1a, t+2);              // refill just-consumed set, 1 tile ahead
    writeA(1);                         // tile t+1 -> buf1 (ra loaded last iter)
    loadA(t+2);
    compute(1, b0b, b1b);              // tile t+1 (odd, buf1)
    loadB(b0b, b1b, t+3);
    writeA(0);                         // tile t+2 -> buf0
    loadA(t+3);
  }
  compute(0, b0a, b1a);                // tile 62
  writeA(1);                           // tile 63
  compute(1, b0b, b1b);                // tile 63

  __syncthreads();             // red aliases kw0..2's sA regions

  // split-K=4 reduce: waves 1..3 dump partials, wave 0 combines (R12-identical)
  float* red = (float*)sA;     // 3 x 64x64 f32 = 48 KB (fits in 64 KB sA)
  if (kw > 0){
    float* rd = red + (size_t)(kw-1)*4096;
    #pragma unroll
    for (int j=0; j<16; ++j){
      int rr = (j&3) + 8*(j>>2) + 4*hsub;          // C/D layout [verified R1..R15]
      rd[(rr   )*64 + r]      = acc00[j];
      rd[(rr   )*64 + 32 + r] = acc01[j];
      rd[(rr+32)*64 + r]      = acc10[j];
      rd[(rr+32)*64 + 32 + r] = acc11[j];
    }
  }
  __syncthreads();
  if (kw == 0){
    #pragma unroll
    for (int j=0; j<16; ++j){
      int rr = (j&3) + 8*(j>>2) + 4*hsub;
      float v00 = acc00[j] + red[(rr   )*64+r]    + red[4096+(rr   )*64+r]    + red[8192+(rr   )*64+r]    + bias[r];
      float v01 = acc01[j] + red[(rr   )*64+32+r] + red[4096+(rr   )*64+32+r] + red[8192+(rr   )*64+32+r] + bias[32+r];
      float v10 = acc10[j] + red[(rr+32)*64+r]    + red[4096+(rr+32)*64+r]    + red[8192+(rr+32)*64+r]    + bias[r];
      float v11 = acc11[j] + red[(rr+32)*64+32+r] + red[4096+(rr+32)*64+32+r] + red[8192+(rr+32)*64+32+r] + bias[32+r];
      G[(size_t)(row0 + rr     )*HCOL + r]      = fmaxf(v00, 0.f);
      G[(size_t)(row0 + rr     )*HCOL + 32 + r] = fmaxf(v01, 0.f);
      G[(size_t)(row0 + rr + 32)*HCOL + r]      = fmaxf(v10, 0.f);
      G[(size_t)(row0 + rr + 32)*HCOL + 32 + r] = fmaxf(v11, 0.f);
    }
  }
}

// ---------------- projection: out[h][n] = sum_f in[n][f]*W[f][h], bf16 out ----------------
template<int F>
__global__ __launch_bounds__(128) void proj_T_kernel(
    const float* __restrict__ in,   // [N][F]
    const float* __restrict__ W,    // [F][64]
    __bf16* __restrict__ out)       // [64][N]
{
  constexpr int FP = F + 4;
  __shared__ float sWt[64*FP];
  __shared__ short sOut[64*136];

  int tid = threadIdx.x;
  for (int e = tid; e < 64*F; e += 128){
    int h = e / F, j = e - h*F;
    sWt[h*FP + j] = W[j*64 + h];
  }
  __syncthreads();

  const size_t n = (size_t)blockIdx.x*128 + tid;
  float rowv[F];
  #pragma unroll
  for (int j=0; j<F; j+=4){
    f32x4v v = *(const f32x4v*)(in + n*F + j);
    rowv[j]=v[0]; rowv[j+1]=v[1]; rowv[j+2]=v[2]; rowv[j+3]=v[3];
  }
  #pragma unroll
  for (int h=0; h<64; ++h){
    float s = 0.f;
    #pragma unroll
    for (int j=0; j<F; j+=4){
      f32x4v w = *(const f32x4v*)&sWt[h*FP + j];
      s += rowv[j]*w[0] + rowv[j+1]*w[1] + rowv[j+2]*w[2] + rowv[j+3]*w[3];
    }
    sOut[h*136 + tid] = __builtin_bit_cast(short, (__bf16)s);
  }
  __syncthreads();

  const size_t n0 = (size_t)blockIdx.x*128;
  #pragma unroll
  for (int pi=0; pi<8; ++pi){
    int p = pi*128 + tid;
    int h = p >> 4, cc = p & 15;
    i32x4 v = *(const i32x4*)&sOut[h*136 + cc*8];
    *(i32x4*)(out + (size_t)h*NNODE + n0 + cc*8) = v;
  }
}

// ---------------- tail MLP: out[n] = relu(g2[n]@Wd1+bd1)@Wd2 + bd2 ----------------
__global__ __launch_bounds__(256) void tail_kernel(
    const float* __restrict__ g2,
    const float* __restrict__ Wd1,
    const float* __restrict__ bd1,
    const float* __restrict__ Wd2,
    const float* __restrict__ bd2,
    float* __restrict__ outp)
{
  __shared__ float sW[64*32];
  __shared__ float sb1[32], sw2[32];
  int tid = threadIdx.x;
  for (int e=tid; e<2048; e+=256) sW[e] = Wd1[e];
  if (tid < 32){ sb1[tid] = bd1[tid]; sw2[tid] = Wd2[tid]; }
  __syncthreads();

  size_t n = (size_t)blockIdx.x*256 + tid;
  float rv[64];
  #pragma unroll
  for (int j=0;j<64;j+=4){
    f32x4v v = *(const f32x4v*)(g2 + n*64 + j);
    rv[j]=v[0]; rv[j+1]=v[1]; rv[j+2]=v[2]; rv[j+3]=v[3];
  }
  float o = 0.f;
  #pragma unroll
  for (int c=0;c<32;++c){
    float s = sb1[c];
    #pragma unroll
    for (int j=0;j<64;++j) s += rv[j]*sW[j*32 + c];
    o += fmaxf(s, 0.f) * sw2[c];
  }
  outp[n] = o + bd2[0];
}

extern "C" void kernel_launch(void* const* d_in, const int* in_sizes, int n_in,
                              void* d_out, int out_size, void* d_ws, size_t ws_size,
                              hipStream_t stream)
{
  const float* x   = (const float*)d_in[0];
  const float* a   = (const float*)d_in[1];
  const float* W1  = (const float*)d_in[2];
  const float* b1  = (const float*)d_in[3];
  const float* W2  = (const float*)d_in[4];
  const float* b2  = (const float*)d_in[5];
  const float* Wd1 = (const float*)d_in[6];
  const float* bd1 = (const float*)d_in[7];
  const float* Wd2 = (const float*)d_in[8];
  const float* bd2 = (const float*)d_in[9];
  float* outp = (float*)d_out;

  char* ws = (char*)d_ws;                       // needs 12 MB
  __bf16* Ht1 = (__bf16*)(ws);                  // [64][16384] bf16, 2 MB
  __bf16* Ht2 = (__bf16*)(ws + (2u<<20));       // 2 MB
  float*  g1  = (float*)(ws + (4u<<20));        // [16384][64] f32, 4 MB
  float*  g2  = (float*)(ws + (8u<<20));        // 4 MB

  proj_T_kernel<32><<<128, 128, 0, stream>>>(x,  W1, Ht1);
  gcn_layer_kernel <<<256, 256, 0, stream>>>(a, Ht1, b1, g1);
  proj_T_kernel<64><<<128, 128, 0, stream>>>(g1, W2, Ht2);
  gcn_layer_kernel <<<256, 256, 0, stream>>>(a, Ht2, b2, g2);
  tail_kernel      <<<64, 256, 0, stream>>>(g2, Wd1, bd1, Wd2, bd2, outp);
}

// Round 17
// 426.548 us; speedup vs baseline: 3.4547x; 1.0664x over previous
//
#include <hip/hip_runtime.h>
#include <hip/hip_bf16.h>

// GGCN: g1=relu(A@(x@W1)+b1); g2=relu(A@(g1@W2)+b2); out=relu(g2@Wd1+bd1)@Wd2+bd2
// N=16384, F=32, H=64, A dense f32 (1.07 GB, read 2x -> HBM floor ~341us).
// R17 = RESTORE R12 (best: 426us). Final structure after 16 rounds:
//  - bf16 MFMA 32x32x16, f32 accumulate (absmax 3.8e-6, 400x under threshold)
//  - BM=64, 4 waves/block, wave kw owns K-quarter (split-K in block)
//  - wave-private LDS dbuf (A 256B/row-visit granule - optimum of {128,256,512})
//  - PLAIN A loads (nontemporal cost 28us: NT defeats partner-line L2 hits)
//  - barrier-free main loop (waves free-run; compiler counted-vmcnt paces)
//  - in-block split-K reduce + bias + relu epilogue.
// Survived perturbations: pacing(R8), kq-per-XCD(R9), granule 128/512(R7/R13),
// BM=128/256(R14/R9), sH-delete+2blk/CU(R15/R16) - all regressed.

typedef __bf16 bf16x8 __attribute__((ext_vector_type(8)));
typedef float  f32x16 __attribute__((ext_vector_type(16)));
typedef float  f32x4v __attribute__((ext_vector_type(4)));
typedef int    i32x4  __attribute__((ext_vector_type(4)));

#define NNODE 16384
#define KDIM  16384
#define HCOL  64

__device__ inline i32x4 pack8(f32x4v a, f32x4v b){
  bf16x8 t;
  t[0]=(__bf16)a[0]; t[1]=(__bf16)a[1]; t[2]=(__bf16)a[2]; t[3]=(__bf16)a[3];
  t[4]=(__bf16)b[0]; t[5]=(__bf16)b[1]; t[6]=(__bf16)b[2]; t[7]=(__bf16)b[3];
  return __builtin_bit_cast(i32x4, t);
}
#define BC(x) __builtin_bit_cast(bf16x8, x)

// ---------------- big kernel: G = relu(A @ Ht^T + bias) ----------------
// block = 256 thr (4 waves). BM=64 rows. wave kw owns K-quarter kw (wave-private
// LDS dbuf, no main-loop barriers). XOR swizzle on 16B chunks: c ^ (row&7).
__global__ __launch_bounds__(256, 1) void gcn_layer_kernel(
    const float* __restrict__ A,      // [16384][16384] f32
    const __bf16* __restrict__ Ht,    // [64][16384] bf16 (transposed H)
    const float* __restrict__ bias,   // [64]
    float* __restrict__ G)            // [16384][64] f32
{
  __shared__ i32x4 sA[4*2*512];   // (kw,buf) x 64 rows x 8 chunks = 64 KB
  __shared__ i32x4 sH[4*2*512];   // (kw,buf) x 64 rows x 8 chunks = 64 KB

  const int tid  = threadIdx.x;
  const int lane = tid & 63;
  const int kw   = tid >> 6;          // K-quarter 0..3
  const int row0 = blockIdx.x * 64;

  const int rA0  = lane >> 3;         // 0..7 staging row-in-group
  const int ccA  = lane & 7;          // staging logical 16B chunk (of 8 per 64k)
  const int swzA = ccA ^ rA0;         // row&7 == rA0 for all staged rows
  const int r    = lane & 31;
  const int hsub = lane >> 5;         // 0/1 k-subgroup within 16-k window
  const int xs   = r & 7;

  const size_t k0 = (size_t)kw * 4096;

  f32x4v ra[16]; i32x4 rh[8];

  const float* pA0 = A + (size_t)(row0 + rA0) * KDIM + k0 + (size_t)ccA*8;
  const i32x4* pH0 = (const i32x4*)Ht + (size_t)rA0 * (KDIM/8) + k0/8 + ccA;

  auto stage_load = [&](int t){
    const float* pA = pA0 + (size_t)t*64;
    #pragma unroll
    for (int pi=0; pi<8; ++pi){                    // rows rA0 + pi*8 (64 rows)
      const float* p = pA + (size_t)pi*8*KDIM;
      ra[2*pi]   = *(const f32x4v*)p;              // plain loads (R12-proven)
      ra[2*pi+1] = *(const f32x4v*)(p+4);
    }
    const i32x4* pH = pH0 + (size_t)t*8;
    #pragma unroll
    for (int pi=0; pi<8; ++pi)
      rh[pi] = pH[(size_t)pi*8*(KDIM/8)];          // Ht: keep L2-cached
  };

  auto stage_write = [&](int buf){
    i32x4* dA = &sA[(kw*2+buf)*512];
    #pragma unroll
    for (int pi=0; pi<8; ++pi)
      dA[(rA0 + pi*8)*8 + swzA] = pack8(ra[2*pi], ra[2*pi+1]);
    i32x4* dH = &sH[(kw*2+buf)*512];
    #pragma unroll
    for (int pi=0; pi<8; ++pi)
      dH[(rA0 + pi*8)*8 + swzA] = rh[pi];
  };

  f32x16 acc00 = {}, acc01 = {}, acc10 = {}, acc11 = {};

  auto compute = [&](int buf){
    const i32x4* bA = &sA[(kw*2+buf)*512];
    const i32x4* bH = &sH[(kw*2+buf)*512];
    #pragma unroll
    for (int kk=0; kk<4; ++kk){
      int c = (kk*2 + hsub) ^ xs;                  // (r+32)&7 == r&7 -> same c
      bf16x8 a0 = BC(bA[r*8 + c]);
      bf16x8 a1 = BC(bA[(r+32)*8 + c]);
      bf16x8 b0 = BC(bH[r*8 + c]);
      bf16x8 b1 = BC(bH[(r+32)*8 + c]);
      acc00 = __builtin_amdgcn_mfma_f32_32x32x16_bf16(a0, b0, acc00, 0,0,0);
      acc01 = __builtin_amdgcn_mfma_f32_32x32x16_bf16(a0, b1, acc01, 0,0,0);
      acc10 = __builtin_amdgcn_mfma_f32_32x32x16_bf16(a1, b0, acc10, 0,0,0);
      acc11 = __builtin_amdgcn_mfma_f32_32x32x16_bf16(a1, b1, acc11, 0,0,0);
    }
  };

  // barrier-free per-wave pipeline over 64 tiles (k-quarter, 64 k each)
  stage_load(0);
  stage_write(0);
  stage_load(1);
  #pragma unroll 1
  for (int t=0; t<63; ++t){
    compute(t&1);
    stage_write((t+1)&1);
    if (t < 62) stage_load(t+2);
  }
  compute(1);                  // tile 63

  __syncthreads();             // red aliases kw0..2's sA regions

  // split-K=4 reduce: waves 1..3 dump partials, wave 0 combines
  float* red = (float*)sA;     // 3 x 64x64 f32 = 48 KB
  if (kw > 0){
    float* rd = red + (size_t)(kw-1)*4096;
    #pragma unroll
    for (int j=0; j<16; ++j){
      int rr = (j&3) + 8*(j>>2) + 4*hsub;          // C/D layout [verified R1..R16]
      rd[(rr   )*64 + r]      = acc00[j];
      rd[(rr   )*64 + 32 + r] = acc01[j];
      rd[(rr+32)*64 + r]      = acc10[j];
      rd[(rr+32)*64 + 32 + r] = acc11[j];
    }
  }
  __syncthreads();
  if (kw == 0){
    #pragma unroll
    for (int j=0; j<16; ++j){
      int rr = (j&3) + 8*(j>>2) + 4*hsub;
      float v00 = acc00[j] + red[(rr   )*64+r]    + red[4096+(rr   )*64+r]    + red[8192+(rr   )*64+r]    + bias[r];
      float v01 = acc01[j] + red[(rr   )*64+32+r] + red[4096+(rr   )*64+32+r] + red[8192+(rr   )*64+32+r] + bias[32+r];
      float v10 = acc10[j] + red[(rr+32)*64+r]    + red[4096+(rr+32)*64+r]    + red[8192+(rr+32)*64+r]    + bias[r];
      float v11 = acc11[j] + red[(rr+32)*64+32+r] + red[4096+(rr+32)*64+32+r] + red[8192+(rr+32)*64+32+r] + bias[32+r];
      G[(size_t)(row0 + rr     )*HCOL + r]      = fmaxf(v00, 0.f);
      G[(size_t)(row0 + rr     )*HCOL + 32 + r] = fmaxf(v01, 0.f);
      G[(size_t)(row0 + rr + 32)*HCOL + r]      = fmaxf(v10, 0.f);
      G[(size_t)(row0 + rr + 32)*HCOL + 32 + r] = fmaxf(v11, 0.f);
    }
  }
}

// ---------------- projection: out[h][n] = sum_f in[n][f]*W[f][h], bf16 out ----------------
template<int F>
__global__ __launch_bounds__(128) void proj_T_kernel(
    const float* __restrict__ in,   // [N][F]
    const float* __restrict__ W,    // [F][64]
    __bf16* __restrict__ out)       // [64][N]
{
  constexpr int FP = F + 4;
  __shared__ float sWt[64*FP];
  __shared__ short sOut[64*136];

  int tid = threadIdx.x;
  for (int e = tid; e < 64*F; e += 128){
    int h = e / F, j = e - h*F;
    sWt[h*FP + j] = W[j*64 + h];
  }
  __syncthreads();

  const size_t n = (size_t)blockIdx.x*128 + tid;
  float rowv[F];
  #pragma unroll
  for (int j=0; j<F; j+=4){
    f32x4v v = *(const f32x4v*)(in + n*F + j);
    rowv[j]=v[0]; rowv[j+1]=v[1]; rowv[j+2]=v[2]; rowv[j+3]=v[3];
  }
  #pragma unroll
  for (int h=0; h<64; ++h){
    float s = 0.f;
    #pragma unroll
    for (int j=0; j<F; j+=4){
      f32x4v w = *(const f32x4v*)&sWt[h*FP + j];
      s += rowv[j]*w[0] + rowv[j+1]*w[1] + rowv[j+2]*w[2] + rowv[j+3]*w[3];
    }
    sOut[h*136 + tid] = __builtin_bit_cast(short, (__bf16)s);
  }
  __syncthreads();

  const size_t n0 = (size_t)blockIdx.x*128;
  #pragma unroll
  for (int pi=0; pi<8; ++pi){
    int p = pi*128 + tid;
    int h = p >> 4, cc = p & 15;
    i32x4 v = *(const i32x4*)&sOut[h*136 + cc*8];
    *(i32x4*)(out + (size_t)h*NNODE + n0 + cc*8) = v;
  }
}

// ---------------- tail MLP: out[n] = relu(g2[n]@Wd1+bd1)@Wd2 + bd2 ----------------
__global__ __launch_bounds__(256) void tail_kernel(
    const float* __restrict__ g2,
    const float* __restrict__ Wd1,
    const float* __restrict__ bd1,
    const float* __restrict__ Wd2,
    const float* __restrict__ bd2,
    float* __restrict__ outp)
{
  __shared__ float sW[64*32];
  __shared__ float sb1[32], sw2[32];
  int tid = threadIdx.x;
  for (int e=tid; e<2048; e+=256) sW[e] = Wd1[e];
  if (tid < 32){ sb1[tid] = bd1[tid]; sw2[tid] = Wd2[tid]; }
  __syncthreads();

  size_t n = (size_t)blockIdx.x*256 + tid;
  float rv[64];
  #pragma unroll
  for (int j=0;j<64;j+=4){
    f32x4v v = *(const f32x4v*)(g2 + n*64 + j);
    rv[j]=v[0]; rv[j+1]=v[1]; rv[j+2]=v[2]; rv[j+3]=v[3];
  }
  float o = 0.f;
  #pragma unroll
  for (int c=0;c<32;++c){
    float s = sb1[c];
    #pragma unroll
    for (int j=0;j<64;++j) s += rv[j]*sW[j*32 + c];
    o += fmaxf(s, 0.f) * sw2[c];
  }
  outp[n] = o + bd2[0];
}

extern "C" void kernel_launch(void* const* d_in, const int* in_sizes, int n_in,
                              void* d_out, int out_size, void* d_ws, size_t ws_size,
                              hipStream_t stream)
{
  const float* x   = (const float*)d_in[0];
  const float* a   = (const float*)d_in[1];
  const float* W1  = (const float*)d_in[2];
  const float* b1  = (const float*)d_in[3];
  const float* W2  = (const float*)d_in[4];
  const float* b2  = (const float*)d_in[5];
  const float* Wd1 = (const float*)d_in[6];
  const float* bd1 = (const float*)d_in[7];
  const float* Wd2 = (const float*)d_in[8];
  const float* bd2 = (const float*)d_in[9];
  float* outp = (float*)d_out;

  char* ws = (char*)d_ws;                       // needs 12 MB
  __bf16* Ht1 = (__bf16*)(ws);                  // [64][16384] bf16, 2 MB
  __bf16* Ht2 = (__bf16*)(ws + (2u<<20));       // 2 MB
  float*  g1  = (float*)(ws + (4u<<20));        // [16384][64] f32, 4 MB
  float*  g2  = (float*)(ws + (8u<<20));        // 4 MB

  proj_T_kernel<32><<<128, 128, 0, stream>>>(x,  W1, Ht1);
  gcn_layer_kernel <<<256, 256, 0, stream>>>(a, Ht1, b1, g1);
  proj_T_kernel<64><<<128, 128, 0, stream>>>(g1, W2, Ht2);
  gcn_layer_kernel <<<256, 256, 0, stream>>>(a, Ht2, b2, g2);
  tail_kernel      <<<64, 256, 0, stream>>>(g2, Wd1, bd1, Wd2, bd2, outp);
}